// Round 10
// baseline (93.825 us; speedup 1.0000x reference)
//
#include <hip/hip_runtime.h>
#include <hip/hip_bf16.h>

#define BB 64
#define TT 32768
#define KK 256
#define LL 2065          // conv out length
#define NLT 9            // l-tiles of 256 per batch
#define NPART (BB*NLT)   // 576 partial slots per channel
#define NJ 19            // j-range for synthesis (P4 packing)
#define HBSTR 132        // k1 epilogue LDS row stride in ushorts (264 B)
#define NPT3 8           // k3 P-tiles per batch (64 packed positions each)

typedef __attribute__((ext_vector_type(8))) short short8;
typedef __attribute__((ext_vector_type(4))) float f32x4;
typedef __attribute__((ext_vector_type(4))) int int4v;
typedef __attribute__((ext_vector_type(2))) unsigned int uint2v;

__device__ __forceinline__ unsigned short f2bf(float f) {
    unsigned u = __builtin_bit_cast(unsigned, f);
    unsigned r = (u + 0x7FFFu + ((u >> 16) & 1u)) >> 16;
    return (unsigned short)r;
}
// packed f32x2 -> bf16x2 (RNE), single instruction
__device__ __forceinline__ unsigned pkbf(float a, float b) {
    unsigned r;
    asm("v_cvt_pk_bf16_f32 %0, %1, %2" : "=v"(r) : "v"(a), "v"(b));
    return r;
}
// async global->LDS, 16B per lane; lds dst = wave-uniform base + lane*16
__device__ __forceinline__ void gload_lds16(const void* g, void* l) {
    __builtin_amdgcn_global_load_lds(
        (const __attribute__((address_space(1))) unsigned int*)g,
        (__attribute__((address_space(3))) unsigned int*)l, 16, 0, 0);
}

// ---------------- k0: gated conv weights -> MFMA fragment-linear bf16 ----------------
// W1f[half][kk(8)][ntL(8)][lane(64)][i(8)]
__global__ void k0_w1f(const float* __restrict__ cw, const float* __restrict__ cgt,
                       unsigned short* __restrict__ W1f)
{
    int idx = blockIdx.x*256 + threadIdx.x;        // 8192 threads, 8 elems each
    int lane = idx & 63, ntL = (idx>>6)&7, kk = (idx>>9)&7, half = idx>>12;
    int o = half*128 + ntL*16 + (lane&15);
    int kbase = kk*32 + ((lane>>4)<<3);
    short8 v;
    #pragma unroll
    for (int i = 0; i < 8; ++i) {
        int gi = o*KK + kbase + i;
        v[i] = (short)f2bf(cw[gi]*(cgt[gi]+1.0f)*0.5f);
    }
    *(short8*)(W1f + (size_t)idx*8) = v;
}

// ---------------- k1: analysis conv (MFMA, swapped), 128-ch halves, 512 threads -------
// acc holds h^T: lane owns c-quad (M=c) at one l (N=l). 2 blocks/CU, 16 waves/CU.
__global__ __launch_bounds__(512, 2)
void k1_conv(const float* __restrict__ x, const float* __restrict__ cs,
             const float* __restrict__ cb, const unsigned short* __restrict__ W1f,
             unsigned short* __restrict__ hout,
             float* __restrict__ psum, float* __restrict__ psq)
{
    __shared__ __align__(16) char smem[13056 + 65536];   // 78592 B
    char* xwinb = smem;                      // padded bf16 x-window (13056 B)
    char* wbuf  = smem + 13056;              // W half (65536 B)
    // epilogue aliases:
    unsigned short* hb = (unsigned short*)smem;          // 256 x HBSTR ushorts = 67584 B
    float* redS = (float*)(smem + 67584);                // [8w][4mt][4g] f32x4 = 2048 B
    float* redQ = (float*)(smem + 67584 + 2048);         // 71680 <= 78592 OK

    const int tid   = threadIdx.x;
    const int half  = blockIdx.x & 1;
    const int ltile = blockIdx.x >> 1;
    const int b     = blockIdx.y;
    const int l0    = ltile * 256;
    const long pos0 = (long)l0*16 - 256;
    const int lane  = tid & 63;
    const int w     = tid >> 6;      // 0..7
    const int wq    = w >> 1;        // l-group (64 l)
    const int wc    = w & 1;         // c-half (64 ch)

    // stage W half (64 KB = 64 chunks of 1 KB) via global_load_lds
    {
        const char* wsrc = (const char*)(W1f + (size_t)half*32768);
        #pragma unroll
        for (int it = 0; it < 8; ++it) {
            int ci = w*8 + it;                        // 0..63
            gload_lds16(wsrc + ci*1024 + lane*16, wbuf + ci*1024);
        }
    }
    // stage x window: 272 groups of 16 elems; group g at bytes 48g..48g+31
    if (tid < 272) {
        const float* xs = x + (size_t)b*TT;
        const int g = tid;
        long base = pos0 + (long)g*16;
        unsigned uu[8];
        if (base >= 0 && base + 16 <= (long)TT) {
            const float4* xv = (const float4*)(xs + base);
            float4 a0 = xv[0], a1 = xv[1], a2 = xv[2], a3 = xv[3];
            uu[0] = pkbf(a0.x, a0.y); uu[1] = pkbf(a0.z, a0.w);
            uu[2] = pkbf(a1.x, a1.y); uu[3] = pkbf(a1.z, a1.w);
            uu[4] = pkbf(a2.x, a2.y); uu[5] = pkbf(a2.z, a2.w);
            uu[6] = pkbf(a3.x, a3.y); uu[7] = pkbf(a3.z, a3.w);
        } else {
            #pragma unroll
            for (int m = 0; m < 16; m += 2) {
                long p = base + m;
                float f0 = (p   >= 0 && p   < TT) ? xs[p]   : 0.0f;
                float f1 = (p+1 >= 0 && p+1 < TT) ? xs[p+1] : 0.0f;
                uu[m>>1] = pkbf(f0, f1);
            }
        }
        int4v w0 = { (int)uu[0], (int)uu[1], (int)uu[2], (int)uu[3] };
        int4v w1 = { (int)uu[4], (int)uu[5], (int)uu[6], (int)uu[7] };
        *(int4v*)(xwinb + 48*g)      = w0;
        *(int4v*)(xwinb + 48*g + 16) = w1;
    }
    __syncthreads();

    // K-loop: barrier-free. acc[mt=c-group 0..3][nt=l-group 0..3]
    f32x4 acc[4][4];
    #pragma unroll
    for (int mt = 0; mt < 4; ++mt)
        #pragma unroll
        for (int nt = 0; nt < 4; ++nt) acc[mt][nt] = (f32x4){0.f,0.f,0.f,0.f};

    const int gq = lane >> 4;
    const int Gt = 16*gq + 16*(gq>>1);                    // {0,16,48,64}
    const int abase = 48*((wq<<6) + (lane & 15)) + Gt;    // + 768*nt + 96*kk

    #pragma unroll
    for (int kk = 0; kk < 8; ++kk) {
        short8 bfx[4], afw[4];
        #pragma unroll
        for (int nt = 0; nt < 4; ++nt)
            bfx[nt] = *(const short8*)(xwinb + abase + nt*768 + kk*96);
        #pragma unroll
        for (int mt = 0; mt < 4; ++mt)
            afw[mt] = *(const short8*)(wbuf + (kk*8 + wc*4 + mt)*1024 + lane*16);
        __builtin_amdgcn_s_setprio(1);
        #pragma unroll
        for (int mt = 0; mt < 4; ++mt)
            #pragma unroll
            for (int nt = 0; nt < 4; ++nt)
                acc[mt][nt] = __builtin_amdgcn_mfma_f32_16x16x32_bf16(afw[mt], bfx[nt], acc[mt][nt], 0, 0, 0);
        __builtin_amdgcn_s_setprio(0);
    }
    __syncthreads();   // xwin/wbuf dead; smem re-used as hb/redS/redQ

    // epilogue: scale/bias/relu; lane holds c-quad at one l -> b64 LDS writes
    const int g  = lane >> 4;
    const int li = lane & 15;
    const bool interior = (l0 + 255 < LL);   // block-uniform: all 256 rows valid
    #pragma unroll
    for (int mt = 0; mt < 4; ++mt) {
        int cq = half*128 + wc*64 + mt*16 + g*4;
        f32x4 cs4 = *(const f32x4*)&cs[cq];
        f32x4 cb4 = *(const f32x4*)&cb[cq];
        f32x4 s4 = (f32x4){0.f,0.f,0.f,0.f};
        f32x4 q4 = (f32x4){0.f,0.f,0.f,0.f};
        #pragma unroll
        for (int nt = 0; nt < 4; ++nt) {
            int lloc = (wq<<6) + nt*16 + li;
            f32x4 hv;
            #pragma unroll
            for (int rr = 0; rr < 4; ++rr)
                hv[rr] = fmaxf(cs4[rr]*(acc[mt][nt][rr] + cb4[rr]), 0.0f);
            uint2v pkv = { pkbf(hv[0], hv[1]), pkbf(hv[2], hv[3]) };
            *(uint2v*)(hb + lloc*HBSTR + wc*64 + mt*16 + g*4) = pkv;
            if (interior) { s4 += hv; q4 += hv*hv; }
            else if (l0 + lloc < LL) { s4 += hv; q4 += hv*hv; }
        }
        #pragma unroll
        for (int d = 1; d < 16; d <<= 1) {
            #pragma unroll
            for (int rr = 0; rr < 4; ++rr) {
                s4[rr] += __shfl_xor(s4[rr], d);
                q4[rr] += __shfl_xor(q4[rr], d);
            }
        }
        if (li == 0) {
            *(f32x4*)&redS[((w*4 + mt)*4 + g)*4] = s4;
            *(f32x4*)&redQ[((w*4 + mt)*4 + g)*4] = q4;
        }
    }
    __syncthreads();

    // coalesced h write: 16 lanes x 16B per row-half (256 B)
    {
        const int rsub = tid >> 4;       // 0..31
        const int cpos = tid & 15;       // 16B chunk within row-half
        #pragma unroll
        for (int it = 0; it < 8; ++it) {
            int row = it*32 + rsub;
            int l = l0 + row;
            if (l < LL) {
                int4v v = *(const int4v*)(hb + row*HBSTR + cpos*8);
                *(int4v*)(hout + (((size_t)(b*LL + l)) << 8) + half*128 + cpos*8) = v;
            }
        }
    }
    if (tid < 128) {
        // c_local = tid: wc' = tid>>6, mt = (tid>>4)&3, g = (tid>>2)&3, rr = tid&3
        int wcc = tid >> 6, mt = (tid >> 4) & 3, gg = (tid >> 2) & 3, rr = tid & 3;
        float s = 0.f, qq = 0.f;
        #pragma unroll
        for (int wqq = 0; wqq < 4; ++wqq) {
            int wi = wqq*2 + wcc;
            s  += redS[((wi*4 + mt)*4 + gg)*4 + rr];
            qq += redQ[((wi*4 + mt)*4 + gg)*4 + rr];
        }
        int c = half*128 + tid;
        int slot = b*NLT + ltile;
        psum[c*NPART + slot] = s;
        psq [c*NPART + slot] = qq;
    }
}

// ---------------- k2: BN stats -> folded synthesis weights W3s[k][c] + SWS ----------------
__global__ __launch_bounds__(256)
void k2_bn(const float* __restrict__ psum, const float* __restrict__ psq,
           const float* __restrict__ bng, const float* __restrict__ bnb,
           const float* __restrict__ ctw, const float* __restrict__ ctg,
           const float* __restrict__ ctscale,
           float* __restrict__ W3s, float* __restrict__ SWS)
{
    __shared__ double rs[4], rq[4];
    __shared__ float s_a, s_bc;
    __shared__ float swl[256];
    const int c = blockIdx.x;
    const int tid = threadIdx.x;
    double s = 0.0, q = 0.0;
    for (int i = tid; i < NPART; i += 256) {
        s += (double)psum[c*NPART + i];
        q += (double)psq [c*NPART + i];
    }
    for (int off = 32; off > 0; off >>= 1) {
        s += __shfl_down(s, off);
        q += __shfl_down(q, off);
    }
    if ((tid & 63) == 0) { rs[tid >> 6] = s; rq[tid >> 6] = q; }
    __syncthreads();
    if (tid == 0) {
        double st = rs[0]+rs[1]+rs[2]+rs[3];
        double qt = rq[0]+rq[1]+rq[2]+rq[3];
        const double cnt = (double)BB * (double)LL;
        double mu = st / cnt;
        double var = qt / cnt - mu*mu;
        float rsig = (float)(1.0 / sqrt(var + 1e-5));
        float a = bng[c] * rsig;
        s_a = a;
        s_bc = bnb[c] - (float)mu * a;
    }
    __syncthreads();
    float a = s_a, bc = s_bc, scl = ctscale[0];
    int gi = c*KK + tid;                          // k = tid
    float wt = ctw[gi] * (ctg[gi] + 1.0f) * 0.5f;
    W3s[tid*KK + c] = scl * a * wt;
    swl[tid] = wt * bc;
    __syncthreads();
    if (tid < 16) {
        float acc2 = 0.0f;
        #pragma unroll
        for (int d = 0; d < 16; ++d) acc2 += swl[d*16 + tid];
        SWS[c*16 + tid] = acc2;
    }
}

__global__ void k2b_const(const float* __restrict__ SWS, const float* __restrict__ ctb,
                          const float* __restrict__ ctscale, float* __restrict__ C2)
{
    int r = threadIdx.x;
    if (r < 16) {
        float s = 0.0f;
        for (int c = 0; c < 256; ++c) s += SWS[c*16 + r];
        C2[r] = ctscale[0] * (s + ctb[0]);
    }
}

// ---------------- k2c: B2f fragment table for synthesis ----------------
__global__ void k2c_b2f(const float* __restrict__ W3s, unsigned short* __restrict__ B2f)
{
    int idx = blockIdx.x*256 + threadIdx.x;        // 38912 threads
    int lane = idx & 63;
    int ntG  = (idx>>6) & 3;
    int kk   = (idx>>8) & 7;
    int j    = idx>>11;
    int c    = kk*32 + ((lane>>4)<<3);
    int r    = lane & 15;
    int d    = ntG + 15 - j;
    short8 v;
    if (d >= 0 && d <= 15) {
        const float* wr = W3s + (size_t)(16*d + r)*KK + c;
        #pragma unroll
        for (int i = 0; i < 8; ++i) v[i] = (short)f2bf(wr[i]);
    } else {
        #pragma unroll
        for (int i = 0; i < 8; ++i) v[i] = 0;
    }
    *(short8*)(B2f + (size_t)idx*8) = v;
}

// ---------------- k3: synthesis conv, 64-P blocks, wave=(ntG,jh), bfr prefetch -------
// out[b][64P+u] = C2[u&15] + sum_{valid j,c} h[b][4P+1+j][c] * B2[(j,c)][u]
__global__ __launch_bounds__(512, 1)
void k3_synth(const unsigned short* __restrict__ h, const unsigned short* __restrict__ B2f,
              const float* __restrict__ C2, float* __restrict__ out)
{
    __shared__ __align__(16) char As[272*512];    // 139264 B; red aliases after compute
    const int tid  = threadIdx.x;
    const int lane = tid & 63;
    const int w    = tid >> 6;       // 0..7
    const int b    = blockIdx.y;
    const int P0   = blockIdx.x * 64;

    const char* hbase = (const char*)h + (((size_t)(b*LL) + 4*P0 + 1) << 9);

    // ---- stage: 34 rows per wave, 2 rows per instr; source-chunk inverse-swizzled ----
    {
        const int rl = lane >> 5;                 // 0/1: row within pair
        #pragma unroll
        for (int i = 0; i < 17; ++i) {
            int r0  = w*34 + i*2;
            int row = r0 + rl;
            int chunk = (lane & 31) ^ ((row >> 2) & 7);
            gload_lds16(hbase + (size_t)row*512 + chunk*16, As + r0*512);
        }
    }
    __syncthreads();

    const int ntG = w & 3;           // u-quadrant (= pr), 16 u values
    const int jh  = w >> 2;          // j-half within the 16 valid j's
    const int li  = lane & 15;
    const int gq  = lane >> 4;
    const int jbase = ntG + jh*8;

    f32x4 acc[4];
    #pragma unroll
    for (int mt = 0; mt < 4; ++mt) acc[mt] = (f32x4){0.f,0.f,0.f,0.f};

    short8 bfA[8], bfB[8];
    #pragma unroll
    for (int kk = 0; kk < 8; ++kk)
        bfA[kk] = *(const short8*)(B2f + (((size_t)(jbase*8 + kk)*4 + ntG)*64 + lane)*8);

#define K3_COMPUTE(JV, BF)                                                          \
    {                                                                               \
        const int j_ = (JV);                                                        \
        _Pragma("unroll")                                                           \
        for (int kk = 0; kk < 8; ++kk) {                                            \
            short8 af[4];                                                           \
            _Pragma("unroll")                                                       \
            for (int mt = 0; mt < 4; ++mt) {                                        \
                int row = 64*mt + 4*li + j_;                                        \
                int p = (kk*4 + gq) ^ ((row >> 2) & 7);                             \
                af[mt] = *(const short8*)(As + row*512 + p*16);                     \
            }                                                                       \
            __builtin_amdgcn_s_setprio(1);                                          \
            _Pragma("unroll")                                                       \
            for (int mt = 0; mt < 4; ++mt)                                          \
                acc[mt] = __builtin_amdgcn_mfma_f32_16x16x32_bf16(af[mt], BF[kk],   \
                                                                  acc[mt], 0, 0, 0);\
            __builtin_amdgcn_s_setprio(0);                                          \
        }                                                                           \
    }

    #pragma unroll 1
    for (int jp = 0; jp < 4; ++jp) {
        const int j0 = jbase + jp*2;
        // prefetch odd j while computing even j
        #pragma unroll
        for (int kk = 0; kk < 8; ++kk)
            bfB[kk] = *(const short8*)(B2f + (((size_t)((j0+1)*8 + kk)*4 + ntG)*64 + lane)*8);
        K3_COMPUTE(j0, bfA);
        if (jp < 3) {
            #pragma unroll
            for (int kk = 0; kk < 8; ++kk)
                bfA[kk] = *(const short8*)(B2f + (((size_t)((j0+2)*8 + kk)*4 + ntG)*64 + lane)*8);
        }
        K3_COMPUTE(j0+1, bfB);
    }
#undef K3_COMPUTE
    __syncthreads();   // all compute reads of As done

    // ---- partials: red[jh][Pl 0..63][68] ----
    float* red = (float*)As;
    #pragma unroll
    for (int mt = 0; mt < 4; ++mt) {
        int u = ntG*16 + li;
        #pragma unroll
        for (int rr = 0; rr < 4; ++rr) {
            int Pl = 16*mt + gq*4 + rr;
            red[jh*4352 + Pl*68 + u] = acc[mt][rr];
        }
    }
    __syncthreads();

    // ---- reduce 2 copies + C2, coalesced store ----
    {
        const float c2v = C2[tid & 15];
        const int u  = tid & 63;
        const int Pb = tid >> 6;         // 0..7
        float* ob = out + (size_t)b*TT + (size_t)P0*64;
        #pragma unroll
        for (int it = 0; it < 8; ++it) {
            int P = it*8 + Pb;
            ob[P*64 + u] = red[P*68 + u] + red[4352 + P*68 + u] + c2v;
        }
    }
}

extern "C" void kernel_launch(void* const* d_in, const int* in_sizes, int n_in,
                              void* d_out, int out_size, void* d_ws, size_t ws_size,
                              hipStream_t stream)
{
    const float* x       = (const float*)d_in[0];
    const float* cw      = (const float*)d_in[1];
    const float* cb      = (const float*)d_in[2];
    const float* cgt     = (const float*)d_in[3];
    const float* cs      = (const float*)d_in[4];
    const float* bng     = (const float*)d_in[5];
    const float* bnb     = (const float*)d_in[6];
    const float* ctw     = (const float*)d_in[7];
    const float* ctb     = (const float*)d_in[8];
    const float* ctg     = (const float*)d_in[9];
    const float* ctscale = (const float*)d_in[10];
    float* out = (float*)d_out;

    char* ws = (char*)d_ws;
    size_t off = 0;
    unsigned short* h    = (unsigned short*)(ws + off); off += (size_t)BB*LL*KK*2;
    float* psum          = (float*)(ws + off);          off += (size_t)KK*NPART*4;
    float* psq           = (float*)(ws + off);          off += (size_t)KK*NPART*4;
    unsigned short* W1f  = (unsigned short*)(ws + off); off += 65536*2;
    float* W3s           = (float*)(ws + off);          off += (size_t)KK*KK*4;
    float* SWS           = (float*)(ws + off);          off += (size_t)KK*16*4;
    float* C2            = (float*)(ws + off);          off += 64;
    unsigned short* B2f  = (unsigned short*)(ws + off); off += (size_t)NJ*8*4*64*8*2;

    k0_w1f  <<<32, 256, 0, stream>>>(cw, cgt, W1f);
    k1_conv <<<dim3(18, BB), 512, 0, stream>>>(x, cs, cb, W1f, h, psum, psq);
    k2_bn   <<<KK, 256, 0, stream>>>(psum, psq, bng, bnb, ctw, ctg, ctscale, W3s, SWS);
    k2b_const<<<1, 64, 0, stream>>>(SWS, ctb, ctscale, C2);
    k2c_b2f <<<152, 256, 0, stream>>>(W3s, B2f);
    k3_synth<<<dim3(NPT3, BB), 512, 0, stream>>>(h, B2f, C2, out);
}

// Round 11
// 83.518 us; speedup vs baseline: 1.1234x; 1.1234x over previous
//
#include <hip/hip_runtime.h>
#include <hip/hip_bf16.h>

#define BB 64
#define TT 32768
#define KK 256
#define LL 2065          // conv out length
#define NLT 9            // l-tiles of 256 per batch
#define NPART (BB*NLT)   // 576 partial slots per channel
#define NJ 19            // j-range for synthesis (P4 packing)
#define HBSTR 72         // k1 epilogue LDS row stride in ushorts (144 B, 16B-aligned)
#define NPT3 8           // k3 P-tiles per batch (64 packed positions each)

typedef __attribute__((ext_vector_type(8))) short short8;
typedef __attribute__((ext_vector_type(4))) float f32x4;
typedef __attribute__((ext_vector_type(4))) int int4v;
typedef __attribute__((ext_vector_type(2))) unsigned int uint2v;

__device__ __forceinline__ unsigned short f2bf(float f) {
    unsigned u = __builtin_bit_cast(unsigned, f);
    unsigned r = (u + 0x7FFFu + ((u >> 16) & 1u)) >> 16;
    return (unsigned short)r;
}
// packed f32x2 -> bf16x2 (RNE), single instruction
__device__ __forceinline__ unsigned pkbf(float a, float b) {
    unsigned r;
    asm("v_cvt_pk_bf16_f32 %0, %1, %2" : "=v"(r) : "v"(a), "v"(b));
    return r;
}
// async global->LDS, 16B per lane; lds dst = wave-uniform base + lane*16
__device__ __forceinline__ void gload_lds16(const void* g, void* l) {
    __builtin_amdgcn_global_load_lds(
        (const __attribute__((address_space(1))) unsigned int*)g,
        (__attribute__((address_space(3))) unsigned int*)l, 16, 0, 0);
}

// ---------------- k0: gated conv weights -> MFMA fragment-linear bf16 ----------------
// W1f[half][kk(8)][ntL(8)][lane(64)][i(8)]
__global__ void k0_w1f(const float* __restrict__ cw, const float* __restrict__ cgt,
                       unsigned short* __restrict__ W1f)
{
    int idx = blockIdx.x*256 + threadIdx.x;        // 8192 threads, 8 elems each
    int lane = idx & 63, ntL = (idx>>6)&7, kk = (idx>>9)&7, half = idx>>12;
    int o = half*128 + ntL*16 + (lane&15);
    int kbase = kk*32 + ((lane>>4)<<3);
    short8 v;
    #pragma unroll
    for (int i = 0; i < 8; ++i) {
        int gi = o*KK + kbase + i;
        v[i] = (short)f2bf(cw[gi]*(cgt[gi]+1.0f)*0.5f);
    }
    *(short8*)(W1f + (size_t)idx*8) = v;
}

// ---------------- k1: analysis conv (MFMA, swapped), 64-channel quarter blocks -------
// acc holds h^T: lane owns c-quad (M=c) at one l (N=l). 3 blocks/CU.  [R9-proven]
__global__ __launch_bounds__(256, 3)
void k1_conv(const float* __restrict__ x, const float* __restrict__ cs,
             const float* __restrict__ cb, const unsigned short* __restrict__ W1f,
             unsigned short* __restrict__ hout,
             float* __restrict__ psum, float* __restrict__ psq)
{
    __shared__ __align__(16) char smem[13056 + 32768];   // 45824 B
    char* xwinb = smem;                      // padded bf16 x-window (13056 B)
    char* wbuf  = smem + 13056;              // W quarter (32768 B)
    // epilogue aliases:
    unsigned short* hb = (unsigned short*)smem;          // 256 x HBSTR ushorts = 36864 B
    float* redS = (float*)(smem + 36864);                // [4w][4mt][4g][4rr] = 1024 B
    float* redQ = (float*)(smem + 36864 + 1024);         // 38912 <= 45824 OK

    const int tid   = threadIdx.x;
    const int q     = blockIdx.x & 3;       // channel quarter (64 ch)
    const int ltile = blockIdx.x >> 2;
    const int b     = blockIdx.y;
    const int l0    = ltile * 256;
    const long pos0 = (long)l0*16 - 256;
    const int lane  = tid & 63;
    const int w     = tid >> 6;

    // stage W quarter (32 KB = 32 chunks of 1 KB) via global_load_lds
    {
        #pragma unroll
        for (int it = 0; it < 8; ++it) {
            int ci = w*8 + it;                        // 0..31
            int kk = ci >> 2, ntl = ci & 3;
            size_t so = (size_t)((((q>>1)*8 + kk)*8 + (q&1)*4 + ntl))*1024;
            gload_lds16((const char*)W1f + so + lane*16, wbuf + ci*1024);
        }
    }
    // stage x window: 272 groups of 16 elems; group g at bytes 48g..48g+31
    {
        const float* xs = x + (size_t)b*TT;
        for (int g = tid; g < 272; g += 256) {
            long base = pos0 + (long)g*16;
            unsigned uu[8];
            if (base >= 0 && base + 16 <= (long)TT) {
                const float4* xv = (const float4*)(xs + base);
                float4 a0 = xv[0], a1 = xv[1], a2 = xv[2], a3 = xv[3];
                uu[0] = pkbf(a0.x, a0.y); uu[1] = pkbf(a0.z, a0.w);
                uu[2] = pkbf(a1.x, a1.y); uu[3] = pkbf(a1.z, a1.w);
                uu[4] = pkbf(a2.x, a2.y); uu[5] = pkbf(a2.z, a2.w);
                uu[6] = pkbf(a3.x, a3.y); uu[7] = pkbf(a3.z, a3.w);
            } else {
                #pragma unroll
                for (int m = 0; m < 16; m += 2) {
                    long p = base + m;
                    float f0 = (p   >= 0 && p   < TT) ? xs[p]   : 0.0f;
                    float f1 = (p+1 >= 0 && p+1 < TT) ? xs[p+1] : 0.0f;
                    uu[m>>1] = pkbf(f0, f1);
                }
            }
            int4v w0 = { (int)uu[0], (int)uu[1], (int)uu[2], (int)uu[3] };
            int4v w1 = { (int)uu[4], (int)uu[5], (int)uu[6], (int)uu[7] };
            *(int4v*)(xwinb + 48*g)      = w0;
            *(int4v*)(xwinb + 48*g + 16) = w1;
        }
    }
    __syncthreads();

    // K-loop: barrier-free. acc[mt=c-group 0..3][nt=l-group 0..3]
    f32x4 acc[4][4];
    #pragma unroll
    for (int mt = 0; mt < 4; ++mt)
        #pragma unroll
        for (int nt = 0; nt < 4; ++nt) acc[mt][nt] = (f32x4){0.f,0.f,0.f,0.f};

    const int gq = lane >> 4;
    const int Gt = 16*gq + 16*(gq>>1);                 // {0,16,48,64}
    const int abase = 48*((w<<6) + (lane & 15)) + Gt;  // + 768*nt + 96*kk

    #pragma unroll
    for (int kk = 0; kk < 8; ++kk) {
        short8 bfx[4], afw[4];
        #pragma unroll
        for (int nt = 0; nt < 4; ++nt)
            bfx[nt] = *(const short8*)(xwinb + abase + nt*768 + kk*96);
        #pragma unroll
        for (int mt = 0; mt < 4; ++mt)
            afw[mt] = *(const short8*)(wbuf + (kk*4 + mt)*1024 + lane*16);
        __builtin_amdgcn_s_setprio(1);
        #pragma unroll
        for (int mt = 0; mt < 4; ++mt)
            #pragma unroll
            for (int nt = 0; nt < 4; ++nt)
                acc[mt][nt] = __builtin_amdgcn_mfma_f32_16x16x32_bf16(afw[mt], bfx[nt], acc[mt][nt], 0, 0, 0);
        __builtin_amdgcn_s_setprio(0);
    }
    __syncthreads();   // xwin/wbuf dead; smem re-used as hb/redS/redQ

    // epilogue: scale/bias/relu; lane holds c-quad at one l -> b64 LDS writes
    const int c0 = q*64;
    const int g  = lane >> 4;
    const int li = lane & 15;
    #pragma unroll
    for (int mt = 0; mt < 4; ++mt) {
        int cq = c0 + mt*16 + g*4;
        f32x4 cs4 = *(const f32x4*)&cs[cq];
        f32x4 cb4 = *(const f32x4*)&cb[cq];
        f32x4 s4 = (f32x4){0.f,0.f,0.f,0.f};
        f32x4 q4 = (f32x4){0.f,0.f,0.f,0.f};
        #pragma unroll
        for (int nt = 0; nt < 4; ++nt) {
            int lloc = (w<<6) + nt*16 + li;
            f32x4 hv;
            #pragma unroll
            for (int rr = 0; rr < 4; ++rr)
                hv[rr] = fmaxf(cs4[rr]*(acc[mt][nt][rr] + cb4[rr]), 0.0f);
            uint2v pkv = { pkbf(hv[0], hv[1]), pkbf(hv[2], hv[3]) };
            *(uint2v*)(hb + lloc*HBSTR + mt*16 + g*4) = pkv;
            if (l0 + lloc < LL) { s4 += hv; q4 += hv*hv; }
        }
        #pragma unroll
        for (int d = 1; d < 16; d <<= 1) {
            #pragma unroll
            for (int rr = 0; rr < 4; ++rr) {
                s4[rr] += __shfl_xor(s4[rr], d);
                q4[rr] += __shfl_xor(q4[rr], d);
            }
        }
        if (li == 0) {
            *(f32x4*)&redS[((w*4 + mt)*4 + g)*4] = s4;
            *(f32x4*)&redQ[((w*4 + mt)*4 + g)*4] = q4;
        }
    }
    __syncthreads();

    // coalesced h write: 8 lanes x 16B per row-quarter (128 B)
    {
        const int rsub = tid >> 3;       // 0..31
        const int cpos = tid & 7;        // 16B chunk within row-quarter
        #pragma unroll
        for (int it = 0; it < 8; ++it) {
            int row = it*32 + rsub;
            int l = l0 + row;
            if (l < LL) {
                int4v v = *(const int4v*)(hb + row*HBSTR + cpos*8);
                *(int4v*)(hout + (((size_t)(b*LL + l)) << 8) + q*64 + cpos*8) = v;
            }
        }
    }
    if (tid < 64) {
        int mt = tid >> 4, gg = (tid >> 2) & 3, rr = tid & 3;
        float s = 0.f, qq = 0.f;
        #pragma unroll
        for (int wv = 0; wv < 4; ++wv) {
            s  += redS[((wv*4 + mt)*4 + gg)*4 + rr];
            qq += redQ[((wv*4 + mt)*4 + gg)*4 + rr];
        }
        int c = c0 + tid;
        int slot = b*NLT + ltile;
        psum[c*NPART + slot] = s;
        psq [c*NPART + slot] = qq;
    }
}

// ---------------- k2: BN stats -> folded synthesis weights W3s[k][c] + SWS ----------------
__global__ __launch_bounds__(256)
void k2_bn(const float* __restrict__ psum, const float* __restrict__ psq,
           const float* __restrict__ bng, const float* __restrict__ bnb,
           const float* __restrict__ ctw, const float* __restrict__ ctg,
           const float* __restrict__ ctscale,
           float* __restrict__ W3s, float* __restrict__ SWS)
{
    __shared__ double rs[4], rq[4];
    __shared__ float s_a, s_bc;
    __shared__ float swl[256];
    const int c = blockIdx.x;
    const int tid = threadIdx.x;
    double s = 0.0, q = 0.0;
    for (int i = tid; i < NPART; i += 256) {
        s += (double)psum[c*NPART + i];
        q += (double)psq [c*NPART + i];
    }
    for (int off = 32; off > 0; off >>= 1) {
        s += __shfl_down(s, off);
        q += __shfl_down(q, off);
    }
    if ((tid & 63) == 0) { rs[tid >> 6] = s; rq[tid >> 6] = q; }
    __syncthreads();
    if (tid == 0) {
        double st = rs[0]+rs[1]+rs[2]+rs[3];
        double qt = rq[0]+rq[1]+rq[2]+rq[3];
        const double cnt = (double)BB * (double)LL;
        double mu = st / cnt;
        double var = qt / cnt - mu*mu;
        float rsig = (float)(1.0 / sqrt(var + 1e-5));
        float a = bng[c] * rsig;
        s_a = a;
        s_bc = bnb[c] - (float)mu * a;
    }
    __syncthreads();
    float a = s_a, bc = s_bc, scl = ctscale[0];
    int gi = c*KK + tid;                          // k = tid
    float wt = ctw[gi] * (ctg[gi] + 1.0f) * 0.5f;
    W3s[tid*KK + c] = scl * a * wt;
    swl[tid] = wt * bc;
    __syncthreads();
    if (tid < 16) {
        float acc2 = 0.0f;
        #pragma unroll
        for (int d = 0; d < 16; ++d) acc2 += swl[d*16 + tid];
        SWS[c*16 + tid] = acc2;
    }
}

__global__ void k2b_const(const float* __restrict__ SWS, const float* __restrict__ ctb,
                          const float* __restrict__ ctscale, float* __restrict__ C2)
{
    int r = threadIdx.x;
    if (r < 16) {
        float s = 0.0f;
        for (int c = 0; c < 256; ++c) s += SWS[c*16 + r];
        C2[r] = ctscale[0] * (s + ctb[0]);
    }
}

// ---------------- k2c: B2f fragment table for synthesis ----------------
__global__ void k2c_b2f(const float* __restrict__ W3s, unsigned short* __restrict__ B2f)
{
    int idx = blockIdx.x*256 + threadIdx.x;        // 38912 threads
    int lane = idx & 63;
    int ntG  = (idx>>6) & 3;
    int kk   = (idx>>8) & 7;
    int j    = idx>>11;
    int c    = kk*32 + ((lane>>4)<<3);
    int r    = lane & 15;
    int d    = ntG + 15 - j;
    short8 v;
    if (d >= 0 && d <= 15) {
        const float* wr = W3s + (size_t)(16*d + r)*KK + c;
        #pragma unroll
        for (int i = 0; i < 8; ++i) v[i] = (short)f2bf(wr[i]);
    } else {
        #pragma unroll
        for (int i = 0; i < 8; ++i) v[i] = 0;
    }
    *(short8*)(B2f + (size_t)idx*8) = v;
}

// ---------------- k3: synthesis conv, j-partitioned waves, full 64x64 tile/wave ------
// out[b][64P+u] = C2[u&15] + sum_{j,c} h[b][4P+1+j][c] * B2[(j,c)][u]
// 8 waves: wave w handles j in {w, w+8, w+16}; per kk: af[4]+bfr[4] -> 16 MFMA (2:1 reuse).
// Block A-LDS traffic 608 KB (was 2 MB); B2f read exactly once per block (608 KB L2).
__global__ __launch_bounds__(512, 1)
void k3_synth(const unsigned short* __restrict__ h, const unsigned short* __restrict__ B2f,
              const float* __restrict__ C2, float* __restrict__ out)
{
    __shared__ __align__(16) char As[272*512];    // 139264 B; red[8][64][68] aliases after
    const int tid  = threadIdx.x;
    const int lane = tid & 63;
    const int w    = tid >> 6;       // 0..7
    const int b    = blockIdx.y;
    const int P0   = blockIdx.x * 64;

    const char* hbase = (const char*)h + (((size_t)(b*LL) + 4*P0 + 1) << 9);

    // ---- stage: 34 rows per wave, 2 rows per instr; source-chunk inverse-swizzled ----
    {
        const int rl = lane >> 5;                 // 0/1: row within pair
        #pragma unroll
        for (int i = 0; i < 17; ++i) {
            int r0  = w*34 + i*2;
            int row = r0 + rl;
            int chunk = (lane & 31) ^ ((row >> 2) & 7);
            gload_lds16(hbase + (size_t)row*512 + chunk*16, As + r0*512);
        }
    }
    __syncthreads();

    const int li = lane & 15;
    const int gq = lane >> 4;

    f32x4 acc[4][4];
    #pragma unroll
    for (int mt = 0; mt < 4; ++mt)
        #pragma unroll
        for (int nt = 0; nt < 4; ++nt) acc[mt][nt] = (f32x4){0.f,0.f,0.f,0.f};

    #pragma unroll 1
    for (int jj = 0; jj < 3; ++jj) {
        const int j = w + jj*8;
        if (j >= NJ) break;
        short8 bfA[4], bfB[4];
        #pragma unroll
        for (int nt = 0; nt < 4; ++nt)
            bfA[nt] = *(const short8*)(B2f + (((size_t)(j*8 + 0)*4 + nt)*64 + lane)*8);
        #pragma unroll
        for (int kk = 0; kk < 8; ++kk) {
            if (kk < 7) {
                #pragma unroll
                for (int nt = 0; nt < 4; ++nt)
                    bfB[nt] = *(const short8*)(B2f + (((size_t)(j*8 + kk+1)*4 + nt)*64 + lane)*8);
            }
            short8 af[4];
            #pragma unroll
            for (int mt = 0; mt < 4; ++mt) {
                int row = 64*mt + 4*li + j;
                int p = (kk*4 + gq) ^ ((row >> 2) & 7);
                af[mt] = *(const short8*)(As + row*512 + p*16);
            }
            __builtin_amdgcn_s_setprio(1);
            #pragma unroll
            for (int mt = 0; mt < 4; ++mt)
                #pragma unroll
                for (int nt = 0; nt < 4; ++nt)
                    acc[mt][nt] = __builtin_amdgcn_mfma_f32_16x16x32_bf16(af[mt], bfA[nt], acc[mt][nt], 0, 0, 0);
            __builtin_amdgcn_s_setprio(0);
            #pragma unroll
            for (int nt = 0; nt < 4; ++nt) bfA[nt] = bfB[nt];
        }
    }
    __syncthreads();   // all compute reads of As done

    // ---- partials: red[w][Pl 0..63][68] ----
    float* red = (float*)As;
    #pragma unroll
    for (int mt = 0; mt < 4; ++mt)
        #pragma unroll
        for (int nt = 0; nt < 4; ++nt) {
            int u = nt*16 + li;
            #pragma unroll
            for (int rr = 0; rr < 4; ++rr) {
                int Pl = 16*mt + gq*4 + rr;
                red[w*4352 + Pl*68 + u] = acc[mt][nt][rr];
            }
        }
    __syncthreads();

    // ---- reduce 8 copies + C2, vectorized, coalesced store ----
    {
        float* ob = out + (size_t)b*TT + (size_t)P0*64;
        #pragma unroll
        for (int it = 0; it < 2; ++it) {
            int item = it*512 + tid;       // 0..1023 = (P 0..63, uq 0..15)
            int P = item >> 4, uq = item & 15;
            f32x4 s = (f32x4){0.f,0.f,0.f,0.f};
            #pragma unroll
            for (int c = 0; c < 8; ++c)
                s += *(const f32x4*)&red[c*4352 + P*68 + uq*4];
            int ub = (uq & 3)*4;
            f32x4 c2v = { C2[ub], C2[ub+1], C2[ub+2], C2[ub+3] };
            *(f32x4*)&ob[P*64 + uq*4] = s + c2v;
        }
    }
}

extern "C" void kernel_launch(void* const* d_in, const int* in_sizes, int n_in,
                              void* d_out, int out_size, void* d_ws, size_t ws_size,
                              hipStream_t stream)
{
    const float* x       = (const float*)d_in[0];
    const float* cw      = (const float*)d_in[1];
    const float* cb      = (const float*)d_in[2];
    const float* cgt     = (const float*)d_in[3];
    const float* cs      = (const float*)d_in[4];
    const float* bng     = (const float*)d_in[5];
    const float* bnb     = (const float*)d_in[6];
    const float* ctw     = (const float*)d_in[7];
    const float* ctb     = (const float*)d_in[8];
    const float* ctg     = (const float*)d_in[9];
    const float* ctscale = (const float*)d_in[10];
    float* out = (float*)d_out;

    char* ws = (char*)d_ws;
    size_t off = 0;
    unsigned short* h    = (unsigned short*)(ws + off); off += (size_t)BB*LL*KK*2;
    float* psum          = (float*)(ws + off);          off += (size_t)KK*NPART*4;
    float* psq           = (float*)(ws + off);          off += (size_t)KK*NPART*4;
    unsigned short* W1f  = (unsigned short*)(ws + off); off += 65536*2;
    float* W3s           = (float*)(ws + off);          off += (size_t)KK*KK*4;
    float* SWS           = (float*)(ws + off);          off += (size_t)KK*16*4;
    float* C2            = (float*)(ws + off);          off += 64;
    unsigned short* B2f  = (unsigned short*)(ws + off); off += (size_t)NJ*8*4*64*8*2;

    k0_w1f  <<<32, 256, 0, stream>>>(cw, cgt, W1f);
    k1_conv <<<dim3(36, BB), 256, 0, stream>>>(x, cs, cb, W1f, h, psum, psq);
    k2_bn   <<<KK, 256, 0, stream>>>(psum, psq, bng, bnb, ctw, ctg, ctscale, W3s, SWS);
    k2b_const<<<1, 64, 0, stream>>>(SWS, ctb, ctscale, C2);
    k2c_b2f <<<152, 256, 0, stream>>>(W3s, B2f);
    k3_synth<<<dim3(NPT3, BB), 512, 0, stream>>>(h, B2f, C2, out);
}